// Round 5
// baseline (274.716 us; speedup 1.0000x reference)
//
#include <hip/hip_runtime.h>

#define NEG_INF (-3.402823466e+38f)  // -FLT_MAX

// Process 16 consecutive row elements held in 4 float4 regs: update the
// running window-4 sum and branchlessly insert each completed window into the
// sorted top-12 list L (descending). KLO: first element index (within this
// chunk) whose window is valid.
template <int KLO>
__device__ __forceinline__ void proc16(const float4 a, const float4 b,
                                       const float4 c, const float4 d,
                                       float h[4], float& w, float L[12]) {
    float xs[16];
    xs[0] = a.x;  xs[1] = a.y;  xs[2] = a.z;  xs[3] = a.w;
    xs[4] = b.x;  xs[5] = b.y;  xs[6] = b.z;  xs[7] = b.w;
    xs[8] = c.x;  xs[9] = c.y;  xs[10] = c.z; xs[11] = c.w;
    xs[12] = d.x; xs[13] = d.y; xs[14] = d.z; xs[15] = d.w;
#pragma unroll
    for (int k = 0; k < 16; ++k) {
        float xv = xs[k];
        w += xv - h[k & 3];   // running 4-window sum (/W folded into epilogue)
        h[k & 3] = xv;        // static index after unroll
        if (k >= KLO) {
            float run = w;
#pragma unroll
            for (int j = 0; j < 12; ++j) {
                float hi = fmaxf(L[j], run);
                run = fminf(L[j], run);
                L[j] = hi;
            }
        }
    }
}

// Tail: 8 elements (2 float4s), all windows valid.
__device__ __forceinline__ void proc8(const float4 a, const float4 b,
                                      float h[4], float& w, float L[12]) {
    float xs[8];
    xs[0] = a.x; xs[1] = a.y; xs[2] = a.z; xs[3] = a.w;
    xs[4] = b.x; xs[5] = b.y; xs[6] = b.z; xs[7] = b.w;
#pragma unroll
    for (int k = 0; k < 8; ++k) {
        float xv = xs[k];
        w += xv - h[k & 3];
        h[k & 3] = xv;
        float run = w;
#pragma unroll
        for (int j = 0; j < 12; ++j) {
            float hi = fmaxf(L[j], run);
            run = fminf(L[j], run);
            L[j] = hi;
        }
    }
}

// Thread-per-row, direct global loads (no LDS staging, no hot-loop barriers,
// no cross-lane ops in compute). Each thread streams its 4000 B row in 64 B
// chunks; consecutive float4s of a thread share a cache line (L1-served), so
// HBM traffic is exactly 1x. Block = 256 threads = 256 rows = 2 outputs.
__global__ __launch_bounds__(256) void ssrp_tpr_kernel(const float* __restrict__ x,
                                                       float* __restrict__ out) {
    __shared__ float wsum[4];
    const int t = threadIdx.x;
    const long long row = (long long)blockIdx.x * 256 + t;
    const float4* __restrict__ p = (const float4*)x + row * 250;

    float L[12];
#pragma unroll
    for (int j = 0; j < 12; ++j) L[j] = NEG_INF;
    float h[4] = {0.f, 0.f, 0.f, 0.f};
    float w = 0.f;

    // depth-2 software pipeline: chunks s (a), s+1 (b) in regs, s+2 loading
    float4 a0 = p[0], a1 = p[1], a2 = p[2], a3 = p[3];
    float4 b0 = p[4], b1 = p[5], b2 = p[6], b3 = p[7];
    p += 8;

    // chunk 0: elements 0..15; first valid window ends at element 3
    proc16<3>(a0, a1, a2, a3, h, w, L);
    a0 = b0; a1 = b1; a2 = b2; a3 = b3;

#pragma unroll 1
    for (int s = 1; s < 61; ++s) {
        b0 = p[0]; b1 = p[1]; b2 = p[2]; b3 = p[3];  // prefetch chunk s+2
        p += 4;
        proc16<0>(a0, a1, a2, a3, h, w, L);          // process chunk s
        a0 = b0; a1 = b1; a2 = b2; a3 = b3;
    }

    // chunk 61 prefetched; tail = cols 248,249 (elements 992..999)
    b0 = p[0]; b1 = p[1];
    proc16<0>(a0, a1, a2, a3, h, w, L);
    proc8(b0, b1, h, w, L);

    // sum of top-12 window sums for this row
    float s12 = 0.f;
#pragma unroll
    for (int j = 0; j < 12; ++j) s12 += L[j];

    // wave reduce: all 64 threads of a wave belong to the same output entry
#pragma unroll
    for (int off = 1; off < 64; off <<= 1) s12 += __shfl_xor(s12, off, 64);

    if ((t & 63) == 0) wsum[t >> 6] = s12;
    __syncthreads();

    // out = sum over 128 rows / (W=4 * K=12 * F=128); written exactly once
    if (t == 0) out[blockIdx.x * 2 + 0] = (wsum[0] + wsum[1]) * (1.0f / 6144.0f);
    if (t == 128) out[blockIdx.x * 2 + 1] = (wsum[2] + wsum[3]) * (1.0f / 6144.0f);
}

extern "C" void kernel_launch(void* const* d_in, const int* in_sizes, int n_in,
                              void* d_out, int out_size, void* d_ws, size_t ws_size,
                              hipStream_t stream) {
    const float* x = (const float*)d_in[0];
    float* out = (float*)d_out;
    const long long total = (long long)in_sizes[0];  // 16*128*128*1000
    const int rows = (int)(total / 1000);            // 262144
    const int blocks = rows / 256;                   // 1024 (= out_size/2)
    hipLaunchKernelGGL(ssrp_tpr_kernel, dim3(blocks), dim3(256), 0, stream, x, out);
}